// Round 9
// baseline (264.700 us; speedup 1.0000x reference)
//
#include <hip/hip_runtime.h>
#include <hip/hip_bf16.h>

typedef float f32x4 __attribute__((ext_vector_type(4)));
typedef __bf16 bf16x8 __attribute__((ext_vector_type(8)));
typedef unsigned long long u64;
typedef u64 u64x2 __attribute__((ext_vector_type(2)));

#define NB 4        // batch
#define NQ 4096
#define NK 4096
#define DIM 512
#define KD 64
#define PKW 128     // packed mask words (u32) per row = NK/32
#define NG64 (1 << 20)      // 64-bit mask groups total = NB*NQ*NK/64
#define PACK_BLOCKS 2048
#define PACK_WAVES (PACK_BLOCKS * 4)

// ---- mask bit-pack, standalone: no LDS -> 8 blocks/CU, 100% occupancy.
// Lane l reads int (g*64 + l); ballot = the 64 bits of group g. 8 groups/iter ILP.
__global__ __launch_bounds__(256, 8) void pack_kernel(
        const int* __restrict__ mask, unsigned* __restrict__ pk) {
    const int tid = threadIdx.x;
    const int w = tid >> 6, l = tid & 63;
    const int wid = blockIdx.x * 4 + w;          // 0..8191
    u64* pk64 = (u64*)pk;
#pragma unroll 1
    for (int g0 = wid * 8; g0 < NG64; g0 += PACK_WAVES * 8) {   // 16 iters
        const int* mb = mask + (long)g0 * 64 + l;
        int m[8];
#pragma unroll
        for (int j = 0; j < 8; j++) m[j] = mb[j * 64];
        u64 bb[8];
#pragma unroll
        for (int j = 0; j < 8; j++) bb[j] = __ballot(m[j] != 0);
        if (l == 0) {
#pragma unroll
            for (int j = 0; j < 4; j++) {
                u64x2 v = {bb[2 * j], bb[2 * j + 1]};
                *(u64x2*)(pk64 + g0 + 2 * j) = v;
            }
        }
    }
}

__device__ inline bf16x8 load_cvt8(const float* __restrict__ p) {
    float4 f0 = *(const float4*)p;
    float4 f1 = *(const float4*)(p + 4);
    bf16x8 r;
    r[0] = (__bf16)f0.x; r[1] = (__bf16)f0.y; r[2] = (__bf16)f0.z; r[3] = (__bf16)f0.w;
    r[4] = (__bf16)f1.x; r[5] = (__bf16)f1.y; r[6] = (__bf16)f1.z; r[7] = (__bf16)f1.w;
    return r;
}

// ---- Q/K/V projection. blocks 0..511: Q rows (scale 1/8 folded). 512..1023: K/V rows.
__global__ __launch_bounds__(256, 4) void proj_kernel(
        const float* __restrict__ x, const float* __restrict__ buf,
        const float* __restrict__ Wq, const float* __restrict__ bq,
        const float* __restrict__ Wk, const float* __restrict__ bk,
        const float* __restrict__ Wv, const float* __restrict__ bv,
        __bf16* __restrict__ Qb, __bf16* __restrict__ Kb, __bf16* __restrict__ Vt) {
    __shared__ __align__(16) float ps[4][32][66];

    const int tid = threadIdx.x;
    const int w = tid >> 6, l = tid & 63;
    const int lr = l & 15, lk = l >> 4;
    const int rg = w >> 1, kh = w & 1;              // row-group, k-half
    const bool is_q = blockIdx.x < 512;
    const int blk = is_q ? blockIdx.x : blockIdx.x - 512;
    const long rowbase = (long)blk * 32 + rg * 16;
    const int kbase = kh * 256;

    if (is_q) {
        f32x4 acc[4] = {};
#pragma unroll 4
        for (int kk = 0; kk < 256; kk += 32) {
            bf16x8 a = load_cvt8(x + (rowbase + lr) * DIM + kbase + kk + lk * 8);
#pragma unroll
            for (int nb = 0; nb < 4; nb++) {
                bf16x8 bw = load_cvt8(Wq + (long)(nb * 16 + lr) * DIM + kbase + kk + lk * 8);
                acc[nb] = __builtin_amdgcn_mfma_f32_16x16x32_bf16(a, bw, acc[nb], 0, 0, 0);
            }
        }
#pragma unroll
        for (int nb = 0; nb < 4; nb++)
#pragma unroll
            for (int i = 0; i < 4; i++)
                ps[kh * 2][rg * 16 + lk * 4 + i][nb * 16 + lr] = acc[nb][i];
        __syncthreads();
        for (int e = tid; e < 2048; e += 256) {
            int row = e >> 6, col = e & 63;
            float v = (ps[0][row][col] + ps[2][row][col] + bq[col]) * 0.125f;  // fold 1/sqrt(KD)
            Qb[((long)blk * 32 + row) * KD + col] = (__bf16)v;
        }
    } else {
        f32x4 acck[4] = {}, accv[4] = {};
#pragma unroll 4
        for (int kk = 0; kk < 256; kk += 32) {
            bf16x8 a = load_cvt8(buf + (rowbase + lr) * DIM + kbase + kk + lk * 8);
#pragma unroll
            for (int nb = 0; nb < 4; nb++) {
                bf16x8 bwk = load_cvt8(Wk + (long)(nb * 16 + lr) * DIM + kbase + kk + lk * 8);
                bf16x8 bwv = load_cvt8(Wv + (long)(nb * 16 + lr) * DIM + kbase + kk + lk * 8);
                acck[nb] = __builtin_amdgcn_mfma_f32_16x16x32_bf16(a, bwk, acck[nb], 0, 0, 0);
                accv[nb] = __builtin_amdgcn_mfma_f32_16x16x32_bf16(a, bwv, accv[nb], 0, 0, 0);
            }
        }
#pragma unroll
        for (int nb = 0; nb < 4; nb++)
#pragma unroll
            for (int i = 0; i < 4; i++) {
                ps[kh * 2 + 0][rg * 16 + lk * 4 + i][nb * 16 + lr] = acck[nb][i];
                ps[kh * 2 + 1][rg * 16 + lk * 4 + i][nb * 16 + lr] = accv[nb][i];
            }
        __syncthreads();
        for (int e = tid; e < 2048; e += 256) {       // K: row-major, col-coalesced
            int row = e >> 6, col = e & 63;
            float v = ps[0][row][col] + ps[2][row][col] + bk[col];
            Kb[((long)blk * 32 + row) * KD + col] = (__bf16)v;
        }
        for (int e = tid; e < 2048; e += 256) {       // V: transposed store, kidx-coalesced
            int row = e & 31, col = e >> 5;
            float v = ps[1][row][col] + ps[3][row][col] + bv[col];
            long grow = (long)blk * 32 + row;
            int b = (int)(grow >> 12), kidx = (int)(grow & 4095);
            Vt[((long)b * KD + col) * NK + kidx] = (__bf16)v;
        }
    }
}

// ---- flash attention. Block = 32 q rows (2 q-groups), 8 waves = qg x 4 key-quarters.
// Halves K/V re-read traffic vs 16-row blocks (512 blocks x 1 MB = 512 MB).
// Fixed-max softmax (logits bounded; masked -> p = 0). Q pre-scaled by 1/8.
__global__ __launch_bounds__(512, 4) void attn_kernel(
        const __bf16* __restrict__ Qb, const __bf16* __restrict__ Kb,
        const __bf16* __restrict__ Vt, const unsigned* __restrict__ pk,
        float* __restrict__ out) {
    // phase 1: per-wave double P tiles: [2][16][72] bf16 at w*4608 (36864 B total)
    // phase 2 (after barrier, reuse): o_s[8][16][66] f32 (33792 B) + ml[8][16] f32 (512 B)
    __shared__ __align__(16) char smem[36864];

    const int tid = threadIdx.x;
    const int w = tid >> 6, l = tid & 63;
    const int lr = l & 15, lk = l >> 4;
    const int b = blockIdx.x >> 7;
    const int q0 = (blockIdx.x & 127) * 32;    // block's 32 q rows
    const int qg = w & 1;                      // wave's q-group
    const int kq = w >> 1;                     // wave's key quarter
    const int qw = q0 + qg * 16;
    const int k0 = kq * 1024;

    const __bf16* Qp = Qb + ((long)b * NQ + qw) * KD;
    const __bf16* Kp = Kb + (long)b * NK * KD;
    const __bf16* Vp = Vt + (long)b * KD * NK;
    const unsigned* mp = pk + ((long)b * NQ + qw) * PKW;

    __bf16 (*pl0)[72] = (__bf16(*)[72])(smem + w * 4608);
    __bf16 (*pl1)[72] = (__bf16(*)[72])(smem + w * 4608 + 2304);

    bf16x8 qa[2];
#pragma unroll
    for (int ks = 0; ks < 2; ks++)
        qa[ks] = *(const bf16x8*)(Qp + (long)lr * KD + ks * 32 + lk * 8);

    f32x4 o[4] = {};
    float l_i[4] = {0.f, 0.f, 0.f, 0.f};

    auto tile = [&](int kt, __bf16 (*pl)[72]) {
        // ---- packed mask words first (early issue): per row i, 2 dwords cover [kt, kt+64)
        unsigned mw0[4], mw1[4];
#pragma unroll
        for (int i = 0; i < 4; i++) {
            uint2 mwv = *(const uint2*)(mp + (long)(lk * 4 + i) * PKW + (kt >> 5));
            mw0[i] = mwv.x; mw1[i] = mwv.y;
        }
        // ---- S = Q K^T  (16 q x 64 k); Q pre-scaled by 1/8
        f32x4 s[4] = {};
#pragma unroll
        for (int ks = 0; ks < 2; ks++)
#pragma unroll
            for (int nb = 0; nb < 4; nb++) {
                bf16x8 kb = *(const bf16x8*)(Kp + (long)(kt + nb * 16 + lr) * KD + ks * 32 + lk * 8);
                s[nb] = __builtin_amdgcn_mfma_f32_16x16x32_bf16(qa[ks], kb, s[nb], 0, 0, 0);
            }
        // ---- fixed-max softmax numerator: p = mask ? exp(s) : 0   (C layout: row=lk*4+i, col=nb*16+lr)
#pragma unroll
        for (int nb = 0; nb < 4; nb++) {
            const unsigned bit = (unsigned)((nb * 16 + lr) & 31);
#pragma unroll
            for (int i = 0; i < 4; i++) {
                unsigned wv = (nb < 2) ? mw0[i] : mw1[i];
                float e = __expf(s[nb][i]);
                float p = ((wv >> bit) & 1u) ? e : 0.0f;
                __bf16 pb = (__bf16)p;
                pl[lk * 4 + i][nb * 16 + lr] = pb;
                l_i[i] += (float)pb;       // denom from the same bf16-rounded values
            }
        }
        // ---- O += P V
#pragma unroll
        for (int ks = 0; ks < 2; ks++) {
            bf16x8 pa = *(const bf16x8*)&pl[lr][ks * 32 + lk * 8];
#pragma unroll
            for (int nb = 0; nb < 4; nb++) {
                bf16x8 vb = *(const bf16x8*)(Vp + (long)(nb * 16 + lr) * NK + kt + ks * 32 + lk * 8);
                o[nb] = __builtin_amdgcn_mfma_f32_16x16x32_bf16(pa, vb, o[nb], 0, 0, 0);
            }
        }
    };

#pragma unroll 1
    for (int kt = k0; kt < k0 + 1024; kt += 128) {
        tile(kt, pl0);
        tile(kt + 64, pl1);
    }

    // ---- reduce denom across the 16 lr lanes (once, at the end)
#pragma unroll
    for (int i = 0; i < 4; i++) {
        float v = l_i[i];
        v += __shfl_xor(v, 1);
        v += __shfl_xor(v, 2);
        v += __shfl_xor(v, 4);
        v += __shfl_xor(v, 8);
        l_i[i] = v;
    }

    // ---- merge: per q-group, plain sums of the 4 key-quarter partials
    __syncthreads();                                  // all waves done with pl regions
    float* o_s = (float*)smem;                        // [8][16][66], part = qg*4+kq
    float* ml  = (float*)(smem + 8 * 16 * 66 * 4);    // [8][16]
    const int part = qg * 4 + kq;
#pragma unroll
    for (int nb = 0; nb < 4; nb++)
#pragma unroll
        for (int i = 0; i < 4; i++)
            o_s[(part * 16 + lk * 4 + i) * 66 + nb * 16 + lr] = o[nb][i];
    if (lr == 0) {
#pragma unroll
        for (int i = 0; i < 4; i++)
            ml[part * 16 + lk * 4 + i] = l_i[i];
    }
    __syncthreads();
    for (int e = tid; e < 2048; e += 512) {
        int row32 = e >> 6, col = e & 63;
        int g = row32 >> 4, row = row32 & 15;
        float L = 0.f, O = 0.f;
#pragma unroll
        for (int kk = 0; kk < 4; kk++) {
            int p = g * 4 + kk;
            L += ml[p * 16 + row];
            O += o_s[(p * 16 + row) * 66 + col];
        }
        out[((long)b * NQ + q0 + row32) * KD + col] = O / L;
    }
}

extern "C" void kernel_launch(void* const* d_in, const int* in_sizes, int n_in,
                              void* d_out, int out_size, void* d_ws, size_t ws_size,
                              hipStream_t stream) {
    const float* x      = (const float*)d_in[0];
    const float* buffer = (const float*)d_in[1];
    const int*   mask   = (const int*)d_in[2];
    const float* Wq     = (const float*)d_in[3];
    const float* bq     = (const float*)d_in[4];
    const float* Wk     = (const float*)d_in[5];
    const float* bk     = (const float*)d_in[6];
    const float* Wv     = (const float*)d_in[7];
    const float* bv     = (const float*)d_in[8];
    float* out = (float*)d_out;

    unsigned* pk = (unsigned*)d_ws;                               // 8.39 MB
    __bf16* Qb = (__bf16*)((char*)d_ws + (size_t)NB * NQ * PKW * 4);
    __bf16* Kb = Qb + (size_t)NB * NQ * KD;
    __bf16* Vt = Kb + (size_t)NB * NK * KD;

    pack_kernel<<<dim3(PACK_BLOCKS), dim3(256), 0, stream>>>(mask, pk);
    proj_kernel<<<dim3(1024), dim3(256), 0, stream>>>(x, buffer, Wq, bq, Wk, bk, Wv, bv, Qb, Kb, Vt);
    attn_kernel<<<dim3(NB * (NQ / 32)), dim3(512), 0, stream>>>(Qb, Kb, Vt, pk, out);
}

// Round 10
// 245.234 us; speedup vs baseline: 1.0794x; 1.0794x over previous
//
#include <hip/hip_runtime.h>
#include <hip/hip_bf16.h>

typedef float f32x4 __attribute__((ext_vector_type(4)));
typedef __bf16 bf16x8 __attribute__((ext_vector_type(8)));
typedef unsigned long long u64;

#define NB 4        // batch
#define NQ 4096
#define NK 4096
#define DIM 512
#define KD 64

__device__ inline bf16x8 load_cvt8(const float* __restrict__ p) {
    float4 f0 = *(const float4*)p;
    float4 f1 = *(const float4*)(p + 4);
    bf16x8 r;
    r[0] = (__bf16)f0.x; r[1] = (__bf16)f0.y; r[2] = (__bf16)f0.z; r[3] = (__bf16)f0.w;
    r[4] = (__bf16)f1.x; r[5] = (__bf16)f1.y; r[6] = (__bf16)f1.z; r[7] = (__bf16)f1.w;
    return r;
}

// ---- Q/K/V projection. blocks 0..511: Q rows (scale 1/8 folded). 512..1023: K/V rows.
__global__ __launch_bounds__(256, 4) void proj_kernel(
        const float* __restrict__ x, const float* __restrict__ buf,
        const float* __restrict__ Wq, const float* __restrict__ bq,
        const float* __restrict__ Wk, const float* __restrict__ bk,
        const float* __restrict__ Wv, const float* __restrict__ bv,
        __bf16* __restrict__ Qb, __bf16* __restrict__ Kb, __bf16* __restrict__ Vt) {
    __shared__ __align__(16) float ps[4][32][66];

    const int tid = threadIdx.x;
    const int w = tid >> 6, l = tid & 63;
    const int lr = l & 15, lk = l >> 4;
    const int rg = w >> 1, kh = w & 1;              // row-group, k-half
    const bool is_q = blockIdx.x < 512;
    const int blk = is_q ? blockIdx.x : blockIdx.x - 512;
    const long rowbase = (long)blk * 32 + rg * 16;
    const int kbase = kh * 256;

    if (is_q) {
        f32x4 acc[4] = {};
#pragma unroll 4
        for (int kk = 0; kk < 256; kk += 32) {
            bf16x8 a = load_cvt8(x + (rowbase + lr) * DIM + kbase + kk + lk * 8);
#pragma unroll
            for (int nb = 0; nb < 4; nb++) {
                bf16x8 bw = load_cvt8(Wq + (long)(nb * 16 + lr) * DIM + kbase + kk + lk * 8);
                acc[nb] = __builtin_amdgcn_mfma_f32_16x16x32_bf16(a, bw, acc[nb], 0, 0, 0);
            }
        }
#pragma unroll
        for (int nb = 0; nb < 4; nb++)
#pragma unroll
            for (int i = 0; i < 4; i++)
                ps[kh * 2][rg * 16 + lk * 4 + i][nb * 16 + lr] = acc[nb][i];
        __syncthreads();
        for (int e = tid; e < 2048; e += 256) {
            int row = e >> 6, col = e & 63;
            float v = (ps[0][row][col] + ps[2][row][col] + bq[col]) * 0.125f;  // fold 1/sqrt(KD)
            Qb[((long)blk * 32 + row) * KD + col] = (__bf16)v;
        }
    } else {
        f32x4 acck[4] = {}, accv[4] = {};
#pragma unroll 4
        for (int kk = 0; kk < 256; kk += 32) {
            bf16x8 a = load_cvt8(buf + (rowbase + lr) * DIM + kbase + kk + lk * 8);
#pragma unroll
            for (int nb = 0; nb < 4; nb++) {
                bf16x8 bwk = load_cvt8(Wk + (long)(nb * 16 + lr) * DIM + kbase + kk + lk * 8);
                bf16x8 bwv = load_cvt8(Wv + (long)(nb * 16 + lr) * DIM + kbase + kk + lk * 8);
                acck[nb] = __builtin_amdgcn_mfma_f32_16x16x32_bf16(a, bwk, acck[nb], 0, 0, 0);
                accv[nb] = __builtin_amdgcn_mfma_f32_16x16x32_bf16(a, bwv, accv[nb], 0, 0, 0);
            }
        }
#pragma unroll
        for (int nb = 0; nb < 4; nb++)
#pragma unroll
            for (int i = 0; i < 4; i++) {
                ps[kh * 2 + 0][rg * 16 + lk * 4 + i][nb * 16 + lr] = acck[nb][i];
                ps[kh * 2 + 1][rg * 16 + lk * 4 + i][nb * 16 + lr] = accv[nb][i];
            }
        __syncthreads();
        for (int e = tid; e < 2048; e += 256) {       // K: row-major, col-coalesced
            int row = e >> 6, col = e & 63;
            float v = ps[0][row][col] + ps[2][row][col] + bk[col];
            Kb[((long)blk * 32 + row) * KD + col] = (__bf16)v;
        }
        for (int e = tid; e < 2048; e += 256) {       // V: transposed store, kidx-coalesced
            int row = e & 31, col = e >> 5;
            float v = ps[1][row][col] + ps[3][row][col] + bv[col];
            long grow = (long)blk * 32 + row;
            int b = (int)(grow >> 12), kidx = (int)(grow & 4095);
            Vt[((long)b * KD + col) * NK + kidx] = (__bf16)v;
        }
    }
}

// ---- flash attention, split-K by 8, fixed-max softmax, IN-REGISTER ballot mask pack.
// Block = 16 q rows, 8 waves; wave w owns keys [w*512, w*512+512). Q pre-scaled by 1/8.
// Per tile: 16 coalesced raw-mask loads (prefetched one tile ahead) -> 16 ballots ->
// per-lane 4-row bit words. Mask is read exactly once, no pack kernel, no intermediate.
__global__ __launch_bounds__(512, 4) void attn_kernel(
        const __bf16* __restrict__ Qb, const __bf16* __restrict__ Kb,
        const __bf16* __restrict__ Vt, const int* __restrict__ mask,
        float* __restrict__ out) {
    // phase 1: per-wave double P tiles: [2][16][72] bf16 at w*4608 (36864 B total)
    // phase 2 (after barrier, reuse): o_s[8][16][66] f32 (33792 B) + ml[8][16] f32 (512 B)
    __shared__ __align__(16) char smem[36864];

    const int tid = threadIdx.x;
    const int w = tid >> 6, l = tid & 63;
    const int lr = l & 15, lk = l >> 4;
    const int b = blockIdx.x >> 8;
    const int q0 = (blockIdx.x & 255) * 16;
    const int k0 = w * 512;

    const __bf16* Qp = Qb + ((long)b * NQ + q0) * KD;
    const __bf16* Kp = Kb + (long)b * NK * KD;
    const __bf16* Vp = Vt + (long)b * KD * NK;
    const int* mp = mask + ((long)b * NQ + q0) * NK + l;   // row r, key k: mp[r*NK + k]

    __bf16 (*pl0)[72] = (__bf16(*)[72])(smem + w * 4608);
    __bf16 (*pl1)[72] = (__bf16(*)[72])(smem + w * 4608 + 2304);

    bf16x8 qa[2];
#pragma unroll
    for (int ks = 0; ks < 2; ks++)
        qa[ks] = *(const bf16x8*)(Qp + (long)lr * KD + ks * 32 + lk * 8);

    f32x4 o[4] = {};
    float l_i[4] = {0.f, 0.f, 0.f, 0.f};

    uint2 mbv[4];   // current tile's mask bits for this lane's 4 rows (row = lk*4+i)
    int   md[16];   // raw-mask prefetch registers (static indexing only)

    // ---- prologue: load + ballot tile k0's mask
#pragma unroll
    for (int r = 0; r < 16; r++) md[r] = mp[(long)r * NK + k0];
#pragma unroll
    for (int r = 0; r < 16; r++) {
        u64 bb = __ballot(md[r] != 0);                 // bit c = mask[row r][k0 + c]
        uint2 b2 = make_uint2((unsigned)bb, (unsigned)(bb >> 32));
        if ((r >> 2) == lk) mbv[r & 3] = b2;           // keep own 4 rows (static idx)
    }

    auto tile = [&](int kt, int kpre, __bf16 (*pl)[72]) {
        // ---- 1. issue raw-mask prefetch for tile kpre (consumed only at step 5)
#pragma unroll
        for (int r = 0; r < 16; r++) md[r] = mp[(long)r * NK + kpre];
        // ---- 2. S = Q K^T  (16 q x 64 k); Q pre-scaled by 1/8
        f32x4 s[4] = {};
#pragma unroll
        for (int ks = 0; ks < 2; ks++)
#pragma unroll
            for (int nb = 0; nb < 4; nb++) {
                bf16x8 kb = *(const bf16x8*)(Kp + (long)(kt + nb * 16 + lr) * KD + ks * 32 + lk * 8);
                s[nb] = __builtin_amdgcn_mfma_f32_16x16x32_bf16(qa[ks], kb, s[nb], 0, 0, 0);
            }
        // ---- 3. fixed-max softmax numerator: p = mask ? exp(s) : 0
        //         (C layout: row = lk*4+i, col = nb*16+lr; bit nb*16+lr of mbv[i])
#pragma unroll
        for (int nb = 0; nb < 4; nb++) {
            const unsigned bit = (unsigned)((nb & 1) * 16 + lr);
#pragma unroll
            for (int i = 0; i < 4; i++) {
                unsigned wv = (nb < 2) ? mbv[i].x : mbv[i].y;
                float e = __expf(s[nb][i]);
                float p = ((wv >> bit) & 1u) ? e : 0.0f;
                __bf16 pb = (__bf16)p;
                pl[lk * 4 + i][nb * 16 + lr] = pb;
                l_i[i] += (float)pb;       // denom from the same bf16-rounded values
            }
        }
        // ---- 4. O += P V
#pragma unroll
        for (int ks = 0; ks < 2; ks++) {
            bf16x8 pa = *(const bf16x8*)&pl[lr][ks * 32 + lk * 8];
#pragma unroll
            for (int nb = 0; nb < 4; nb++) {
                bf16x8 vb = *(const bf16x8*)(Vp + (long)(nb * 16 + lr) * NK + kt + ks * 32 + lk * 8);
                o[nb] = __builtin_amdgcn_mfma_f32_16x16x32_bf16(pa, vb, o[nb], 0, 0, 0);
            }
        }
        // ---- 5. ballot the prefetched mask into bit-words for the next tile
#pragma unroll
        for (int r = 0; r < 16; r++) {
            u64 bb = __ballot(md[r] != 0);
            uint2 b2 = make_uint2((unsigned)bb, (unsigned)(bb >> 32));
            if ((r >> 2) == lk) mbv[r & 3] = b2;
        }
    };

#pragma unroll 1
    for (int kt = k0; kt < k0 + 512; kt += 128) {
        tile(kt, kt + 64, pl0);
        int nx = (kt + 128 < k0 + 512) ? kt + 128 : k0;   // wrap on last (result discarded)
        tile(kt + 64, nx, pl1);
    }

    // ---- reduce denom across the 16 lr lanes (once, at the end)
#pragma unroll
    for (int i = 0; i < 4; i++) {
        float v = l_i[i];
        v += __shfl_xor(v, 1);
        v += __shfl_xor(v, 2);
        v += __shfl_xor(v, 4);
        v += __shfl_xor(v, 8);
        l_i[i] = v;
    }

    // ---- split-K merge: plain sums of (o, l)
    __syncthreads();                                  // all waves done with pl regions
    float* o_s = (float*)smem;                        // [8][16][66]
    float* ml  = (float*)(smem + 8 * 16 * 66 * 4);    // [8][16]
#pragma unroll
    for (int nb = 0; nb < 4; nb++)
#pragma unroll
        for (int i = 0; i < 4; i++)
            o_s[(w * 16 + lk * 4 + i) * 66 + nb * 16 + lr] = o[nb][i];
    if (lr == 0) {
#pragma unroll
        for (int i = 0; i < 4; i++)
            ml[w * 16 + lk * 4 + i] = l_i[i];
    }
    __syncthreads();
    for (int e = tid; e < 1024; e += 512) {
        int row = e >> 6, col = e & 63;
        float L = 0.f, O = 0.f;
#pragma unroll
        for (int ww = 0; ww < 8; ww++) {
            L += ml[ww * 16 + row];
            O += o_s[(ww * 16 + row) * 66 + col];
        }
        out[((long)b * NQ + q0 + row) * KD + col] = O / L;
    }
}

extern "C" void kernel_launch(void* const* d_in, const int* in_sizes, int n_in,
                              void* d_out, int out_size, void* d_ws, size_t ws_size,
                              hipStream_t stream) {
    const float* x      = (const float*)d_in[0];
    const float* buffer = (const float*)d_in[1];
    const int*   mask   = (const int*)d_in[2];
    const float* Wq     = (const float*)d_in[3];
    const float* bq     = (const float*)d_in[4];
    const float* Wk     = (const float*)d_in[5];
    const float* bk     = (const float*)d_in[6];
    const float* Wv     = (const float*)d_in[7];
    const float* bv     = (const float*)d_in[8];
    float* out = (float*)d_out;

    __bf16* Qb = (__bf16*)d_ws;
    __bf16* Kb = Qb + (size_t)NB * NQ * KD;
    __bf16* Vt = Kb + (size_t)NB * NK * KD;

    proj_kernel<<<dim3(1024), dim3(256), 0, stream>>>(x, buffer, Wq, bq, Wk, bk, Wv, bv, Qb, Kb, Vt);
    attn_kernel<<<dim3(NB * (NQ / 16)), dim3(512), 0, stream>>>(Qb, Kb, Vt, mask, out);
}